// Round 7
// baseline (48.617 us; speedup 1.0000x reference)
//
#include <hip/hip_runtime.h>

#define N_SPK 1024
#define M_UTT 16
#define D_DIM 512

typedef __attribute__((ext_vector_type(8))) short bf16x8;
typedef __attribute__((ext_vector_type(4))) float f32x4;

__device__ __forceinline__ float wave_sum64(float v) {
  #pragma unroll
  for (int off = 32; off >= 1; off >>= 1) v += __shfl_xor(v, off, 64);
  return v;
}

__device__ __forceinline__ unsigned short f2bf(float x) {
  unsigned int u = __float_as_uint(x);
  unsigned int r = (u + 0x7FFFu + ((u >> 16) & 1u)) >> 16;  // RNE
  return (unsigned short)r;
}

__device__ __forceinline__ unsigned int pack_bf16(float a, float b) {
  return (unsigned int)f2bf(a) | ((unsigned int)f2bf(b) << 16);
}

__device__ __forceinline__ void gload_lds16(const void* g, void* l) {
  __builtin_amdgcn_global_load_lds(
      (const __attribute__((address_space(1))) void*)g,
      (__attribute__((address_space(3))) void*)l, 16, 0, 0);
}

// Kernel 1: per speaker n — centroid unit vec (bf16), normalized embeddings
// (bf16), exact fp32 LOO diagonal logit pos = w*(diag+eps)+b.  (unchanged)
__global__ __launch_bounds__(256) void prep_kernel(
    const float* __restrict__ emb, const float* __restrict__ wp,
    const float* __restrict__ bp, unsigned int* __restrict__ eU,
    unsigned int* __restrict__ cU, float* __restrict__ pos_out)
{
  const int n = blockIdx.x;
  const int t = threadIdx.x;
  __shared__ float es[M_UTT * D_DIM];
  __shared__ float Sd[D_DIM];
  __shared__ float red[4];
  __shared__ float inv_s[M_UTT];

  const float* base = emb + (size_t)n * (M_UTT * D_DIM);
  #pragma unroll
  for (int i = 0; i < 8; ++i) {
    int s = t + i * 256;
    reinterpret_cast<float4*>(es)[s] = reinterpret_cast<const float4*>(base)[s];
  }
  __syncthreads();

  #pragma unroll
  for (int rep = 0; rep < 2; ++rep) {
    int d = t + rep * 256;
    float s = 0.f;
    #pragma unroll
    for (int m = 0; m < M_UTT; ++m) s += es[m * D_DIM + d];
    Sd[d] = s;
  }
  __syncthreads();

  float p = 0.f;
  #pragma unroll
  for (int rep = 0; rep < 2; ++rep) {
    int d = t + rep * 256;
    float c = Sd[d] * (1.f / M_UTT);
    p += c * c;
  }
  p = wave_sum64(p);
  if ((t & 63) == 0) red[t >> 6] = p;
  __syncthreads();
  float cn2 = red[0] + red[1] + red[2] + red[3];
  float invc = 1.f / fmaxf(sqrtf(cn2), 1e-8f);

  {
    int d = t * 2;
    float c0 = Sd[d] * (1.f / M_UTT) * invc;
    float c1 = Sd[d + 1] * (1.f / M_UTT) * invc;
    cU[n * 256 + t] = pack_bf16(c0, c1);
  }

  const int wid = t >> 6, lane = t & 63;
  const float w = *wp, b = *bp;
  for (int m = wid; m < M_UTT; m += 4) {
    float dot = 0.f, ne = 0.f, nl = 0.f;
    #pragma unroll
    for (int r = 0; r < 8; ++r) {
      int d = lane + r * 64;
      float e = es[m * D_DIM + d];
      float l = Sd[d] - e;
      dot += e * l; ne += e * e; nl += l * l;
    }
    dot = wave_sum64(dot); ne = wave_sum64(ne); nl = wave_sum64(nl);
    if (lane == 0) {
      float inv_e = 1.f / fmaxf(sqrtf(ne), 1e-8f);
      float inv_l = 1.f / fmaxf(sqrtf(nl) * (1.f / (M_UTT - 1)), 1e-8f);
      float diag = dot * (1.f / (M_UTT - 1)) * inv_e * inv_l;
      pos_out[n * M_UTT + m] = w * (diag + 1e-6f) + b;
      inv_s[m] = inv_e;
    }
  }
  __syncthreads();

  #pragma unroll
  for (int i = 0; i < 16; ++i) {
    int p2 = t + i * 256;
    int m = p2 >> 8;
    int d = (p2 & 255) * 2;
    float sc = inv_s[m];
    float x0 = es[m * D_DIM + d] * sc;
    float x1 = es[m * D_DIM + d + 1] * sc;
    eU[(size_t)n * 4096 + p2] = pack_bf16(x0, x1);
  }
}

// Kernel 2: BM=128 x BN=256 tile, BK=32, 4 waves (wn = wv), 256 threads,
// ring-of-3 LDS buffers (24KB each -> 74.5KB total -> 2 blocks/CU),
// counted vmcnt pipeline (6 loads/tile, steady vmcnt(6)), row-pair XOR
// swizzle, fused exp epilogue. Grid 512 = 2 blocks/CU.
#define NTILES 16   // 512 / 32
#define BUFSZ 24576 // A 8KB + B 16KB

struct StageOff {
  unsigned int gA0, gA1, gB0, gB1, gB2, gB3;
  int a0, a1, b0, b1, b2, b3;
};

__device__ __forceinline__ void stage_tile(
    const char* __restrict__ eU, const char* __restrict__ cU,
    char* AsB, int tt, const StageOff& so)
{
  char* buf = AsB + (tt % 3) * BUFSZ;
  const int d0 = tt * 64;                 // 32 k-elems * 2B
  gload_lds16(eU + so.gA0 + d0, buf + so.a0);
  gload_lds16(eU + so.gA1 + d0, buf + so.a1);
  gload_lds16(cU + so.gB0 + d0, buf + 8192 + so.b0);
  gload_lds16(cU + so.gB1 + d0, buf + 8192 + so.b1);
  gload_lds16(cU + so.gB2 + d0, buf + 8192 + so.b2);
  gload_lds16(cU + so.gB3 + d0, buf + 8192 + so.b3);
}

__device__ __forceinline__ void compute_tile(
    const char* AsB, int tt, int wv, int laneoff, f32x4 acc[8][4])
{
  const char* Ab = AsB + (tt % 3) * BUFSZ;
  const char* Bb = Ab + 8192;
  bf16x8 af[8], bfr[4];
  #pragma unroll
  for (int mi = 0; mi < 8; ++mi)
    af[mi] = *reinterpret_cast<const bf16x8*>(Ab + mi * 1024 + laneoff);
  #pragma unroll
  for (int nj = 0; nj < 4; ++nj)
    bfr[nj] = *reinterpret_cast<const bf16x8*>(
        Bb + wv * 4096 + nj * 1024 + laneoff);
  __builtin_amdgcn_s_setprio(1);
  #pragma unroll
  for (int mi = 0; mi < 8; ++mi)
    #pragma unroll
    for (int nj = 0; nj < 4; ++nj)
      acc[mi][nj] = __builtin_amdgcn_mfma_f32_16x16x32_bf16(
          af[mi], bfr[nj], acc[mi][nj], 0, 0, 0);
  __builtin_amdgcn_s_setprio(0);
}

__global__ __launch_bounds__(256, 2) void mfma_kernel(
    const char* __restrict__ eU, const char* __restrict__ cU,
    const float* __restrict__ pos, const float* __restrict__ wp,
    const float* __restrict__ bp, float* __restrict__ partial)
{
  __shared__ char AsB[3 * BUFSZ];
  __shared__ float pos_l[128];
  __shared__ float rowsum[4][128];

  const int t = threadIdx.x;
  const int lane = t & 63;
  const int wv = t >> 6;               // 0..3 == wn

  // XCD swizzle: 512 blocks, 8 XCDs; each XCD-pair owns one 256-col B slice.
  const int bid = blockIdx.x;
  const int sw = (bid & 7) * 64 + (bid >> 3);
  const int cb = sw >> 7, rb = sw & 127;
  const int row0 = rb * 128, col0 = cb * 256;

  const float w = *wp, b = *bp;        // uniform -> s_load (lgkm, not vmcnt)
  const float bb = w * 1e-6f + b;

  if (t < 128) pos_l[t] = pos[row0 + t];

  // staging offsets: chunk = 16 rows; lane l -> linear LDS slot l*16 within
  // chunk; source (row = chunk*16 + 2*(l>>3) + p, seg=(l&7)^(l>>3)) so the
  // LDS image is the row-pair XOR-swizzled layout.
  StageOff so;
  {
    const int rp = lane >> 3;
    const int seg = (lane & 7) ^ rp;
    const int p = seg >> 2, ks = seg & 3;
    const int rloc = 2 * rp + p;
    so.gA0 = (unsigned int)(row0 + (wv * 2 + 0) * 16 + rloc) * 1024u + ks * 16;
    so.gA1 = (unsigned int)(row0 + (wv * 2 + 1) * 16 + rloc) * 1024u + ks * 16;
    so.gB0 = (unsigned int)(col0 + (wv * 4 + 0) * 16 + rloc) * 1024u + ks * 16;
    so.gB1 = (unsigned int)(col0 + (wv * 4 + 1) * 16 + rloc) * 1024u + ks * 16;
    so.gB2 = (unsigned int)(col0 + (wv * 4 + 2) * 16 + rloc) * 1024u + ks * 16;
    so.gB3 = (unsigned int)(col0 + (wv * 4 + 3) * 16 + rloc) * 1024u + ks * 16;
    so.a0 = (wv * 2 + 0) * 1024;
    so.a1 = (wv * 2 + 1) * 1024;
    so.b0 = (wv * 4 + 0) * 1024;
    so.b1 = (wv * 4 + 1) * 1024;
    so.b2 = (wv * 4 + 2) * 1024;
    so.b3 = (wv * 4 + 3) * 1024;
  }
  // fragment read offset: row j = lane&15, kchunk g = lane>>4
  const int j = lane & 15, g = lane >> 4;
  const int laneoff = (j >> 1) * 128 + ((((j & 1) * 4 + g) ^ (j >> 1)) * 16);

  f32x4 acc[8][4] = {};

  __syncthreads();   // pos_l visible + vmcnt drained (exact counting after)

  stage_tile(eU, cU, AsB, 0, so);
  stage_tile(eU, cU, AsB, 1, so);

  for (int tt = 0; tt < NTILES; ++tt) {
    if (tt < NTILES - 1)
      asm volatile("s_waitcnt vmcnt(6)" ::: "memory");   // tile tt landed
    else
      asm volatile("s_waitcnt vmcnt(0)" ::: "memory");
    __builtin_amdgcn_s_barrier();                        // visible to all waves
    if (tt + 2 < NTILES) stage_tile(eU, cU, AsB, tt + 2, so);
    compute_tile(AsB, tt, wv, laneoff, acc);
    __builtin_amdgcn_s_barrier();                        // reads done b4 reuse
  }

  // fused epilogue: arg = w*acc + bb (diag -> pos), exp, per-row sums
  float esum[8][4];
  #pragma unroll
  for (int mi = 0; mi < 8; ++mi)
    #pragma unroll
    for (int rg = 0; rg < 4; ++rg) esum[mi][rg] = 0.f;

  #pragma unroll
  for (int nj = 0; nj < 4; ++nj) {
    const int kg = col0 + wv * 64 + nj * 16 + (lane & 15);
    #pragma unroll
    for (int mi = 0; mi < 8; ++mi) {
      #pragma unroll
      for (int rg = 0; rg < 4; ++rg) {
        const int r_loc = mi * 16 + (lane >> 4) * 4 + rg;
        float arg = w * acc[mi][nj][rg] + bb;
        if (kg == ((row0 + r_loc) >> 4)) arg = pos_l[r_loc];
        esum[mi][rg] += __expf(arg);
      }
    }
  }
  #pragma unroll
  for (int mi = 0; mi < 8; ++mi)
    #pragma unroll
    for (int rg = 0; rg < 4; ++rg) {
      float v = esum[mi][rg];
      v += __shfl_xor(v, 1, 64);
      v += __shfl_xor(v, 2, 64);
      v += __shfl_xor(v, 4, 64);
      v += __shfl_xor(v, 8, 64);
      esum[mi][rg] = v;
    }
  if ((lane & 15) == 0) {
    #pragma unroll
    for (int mi = 0; mi < 8; ++mi)
      #pragma unroll
      for (int rg = 0; rg < 4; ++rg)
        rowsum[wv][mi * 16 + (lane >> 4) * 4 + rg] = esum[mi][rg];
  }
  __syncthreads();
  if (t < 128)
    partial[(size_t)cb * (N_SPK * M_UTT) + row0 + t] =
        rowsum[0][t] + rowsum[1][t] + rowsum[2][t] + rowsum[3][t];
}

// Kernel 3: fused log-sum + global reduce, single block (deterministic).
__global__ __launch_bounds__(1024) void finalize_kernel(
    const float* __restrict__ partial, const float* __restrict__ pos,
    float* __restrict__ out)
{
  const int t = threadIdx.x;
  float v = 0.f;
  #pragma unroll
  for (int i = 0; i < 16; ++i) {
    const int r = t + i * 1024;
    float s = partial[r] + partial[16384 + r] + partial[32768 + r] +
              partial[49152 + r];
    v += logf(s + 1e-6f) - pos[r];
  }
  v = wave_sum64(v);
  __shared__ float red[16];
  if ((t & 63) == 0) red[t >> 6] = v;
  __syncthreads();
  if (t == 0) {
    float s = 0.f;
    #pragma unroll
    for (int i = 0; i < 16; ++i) s += red[i];
    out[0] = s;
  }
}

extern "C" void kernel_launch(void* const* d_in, const int* in_sizes, int n_in,
                              void* d_out, int out_size, void* d_ws, size_t ws_size,
                              hipStream_t stream) {
  const float* emb = (const float*)d_in[0];
  const float* wp  = (const float*)d_in[1];
  const float* bp  = (const float*)d_in[2];
  float* out = (float*)d_out;

  char* wsb = (char*)d_ws;
  unsigned int* eU  = (unsigned int*)wsb;                       // 16,777,216 B
  unsigned int* cU  = (unsigned int*)(wsb + 16777216);          //  1,048,576 B
  float* pos        = (float*)(wsb + 16777216 + 1048576);       //     65,536 B
  float* partial    = (float*)(wsb + 16777216 + 1048576 + 65536);   // 262,144 B

  prep_kernel<<<N_SPK, 256, 0, stream>>>(emb, wp, bp, eU, cU, pos);
  mfma_kernel<<<512, 256, 0, stream>>>(
      (const char*)eU, (const char*)cU, pos, wp, bp, partial);
  finalize_kernel<<<1, 1024, 0, stream>>>(partial, pos, out);
}

// Round 8
// 44.870 us; speedup vs baseline: 1.0835x; 1.0835x over previous
//
#include <hip/hip_runtime.h>

#define N_SPK 1024
#define M_UTT 16
#define D_DIM 512

typedef __attribute__((ext_vector_type(8))) short bf16x8;
typedef __attribute__((ext_vector_type(4))) float f32x4;

__device__ __forceinline__ float wave_sum64(float v) {
  #pragma unroll
  for (int off = 32; off >= 1; off >>= 1) v += __shfl_xor(v, off, 64);
  return v;
}

__device__ __forceinline__ unsigned short f2bf(float x) {
  unsigned int u = __float_as_uint(x);
  unsigned int r = (u + 0x7FFFu + ((u >> 16) & 1u)) >> 16;  // RNE
  return (unsigned short)r;
}

__device__ __forceinline__ unsigned int pack_bf16(float a, float b) {
  return (unsigned int)f2bf(a) | ((unsigned int)f2bf(b) << 16);
}

__device__ __forceinline__ void gload_lds16(const void* g, void* l) {
  __builtin_amdgcn_global_load_lds(
      (const __attribute__((address_space(1))) void*)g,
      (__attribute__((address_space(3))) void*)l, 16, 0, 0);
}

__device__ __forceinline__ void barrier_pin() {
  __builtin_amdgcn_sched_barrier(0);
  __builtin_amdgcn_s_barrier();
  __builtin_amdgcn_sched_barrier(0);
}

__device__ __forceinline__ void lgkm0() {
  asm volatile("s_waitcnt lgkmcnt(0)" ::: "memory");
  __builtin_amdgcn_sched_barrier(0);
}

// Kernel 1: per speaker n — centroid unit vec (bf16), normalized embeddings
// (bf16), exact fp32 LOO diagonal logit pos = w*(diag+eps)+b.  (unchanged)
__global__ __launch_bounds__(256) void prep_kernel(
    const float* __restrict__ emb, const float* __restrict__ wp,
    const float* __restrict__ bp, unsigned int* __restrict__ eU,
    unsigned int* __restrict__ cU, float* __restrict__ pos_out)
{
  const int n = blockIdx.x;
  const int t = threadIdx.x;
  __shared__ float es[M_UTT * D_DIM];
  __shared__ float Sd[D_DIM];
  __shared__ float red[4];
  __shared__ float inv_s[M_UTT];

  const float* base = emb + (size_t)n * (M_UTT * D_DIM);
  #pragma unroll
  for (int i = 0; i < 8; ++i) {
    int s = t + i * 256;
    reinterpret_cast<float4*>(es)[s] = reinterpret_cast<const float4*>(base)[s];
  }
  __syncthreads();

  #pragma unroll
  for (int rep = 0; rep < 2; ++rep) {
    int d = t + rep * 256;
    float s = 0.f;
    #pragma unroll
    for (int m = 0; m < M_UTT; ++m) s += es[m * D_DIM + d];
    Sd[d] = s;
  }
  __syncthreads();

  float p = 0.f;
  #pragma unroll
  for (int rep = 0; rep < 2; ++rep) {
    int d = t + rep * 256;
    float c = Sd[d] * (1.f / M_UTT);
    p += c * c;
  }
  p = wave_sum64(p);
  if ((t & 63) == 0) red[t >> 6] = p;
  __syncthreads();
  float cn2 = red[0] + red[1] + red[2] + red[3];
  float invc = 1.f / fmaxf(sqrtf(cn2), 1e-8f);

  {
    int d = t * 2;
    float c0 = Sd[d] * (1.f / M_UTT) * invc;
    float c1 = Sd[d + 1] * (1.f / M_UTT) * invc;
    cU[n * 256 + t] = pack_bf16(c0, c1);
  }

  const int wid = t >> 6, lane = t & 63;
  const float w = *wp, b = *bp;
  for (int m = wid; m < M_UTT; m += 4) {
    float dot = 0.f, ne = 0.f, nl = 0.f;
    #pragma unroll
    for (int r = 0; r < 8; ++r) {
      int d = lane + r * 64;
      float e = es[m * D_DIM + d];
      float l = Sd[d] - e;
      dot += e * l; ne += e * e; nl += l * l;
    }
    dot = wave_sum64(dot); ne = wave_sum64(ne); nl = wave_sum64(nl);
    if (lane == 0) {
      float inv_e = 1.f / fmaxf(sqrtf(ne), 1e-8f);
      float inv_l = 1.f / fmaxf(sqrtf(nl) * (1.f / (M_UTT - 1)), 1e-8f);
      float diag = dot * (1.f / (M_UTT - 1)) * inv_e * inv_l;
      pos_out[n * M_UTT + m] = w * (diag + 1e-6f) + b;
      inv_s[m] = inv_e;
    }
  }
  __syncthreads();

  #pragma unroll
  for (int i = 0; i < 16; ++i) {
    int p2 = t + i * 256;
    int m = p2 >> 8;
    int d = (p2 & 255) * 2;
    float sc = inv_s[m];
    float x0 = es[m * D_DIM + d] * sc;
    float x1 = es[m * D_DIM + d + 1] * sc;
    eU[(size_t)n * 4096 + p2] = pack_bf16(x0, x1);
  }
}

// ---------------- 8-phase 256x256 MFMA GEMM with fused exp epilogue --------
// BM=BN=256, BK=64, 8 waves (wm=wv>>2 in 0..1, wn=wv&3 in 0..3).
// LDS: A dbuf 2x32KB, B dbuf 2x32KB. Half-tile = 128 rows x 64k = 16KB = 2
// gload_lds_dwordx4 rounds (512 thr x 16B). Stream order per tile:
// [B-lo, B-hi, A-lo, A-hi]; stage offset +6 phases; steady vmcnt(4)/K-tile.
#define NKT 8   // 512 / 64

struct Pipe {
  const char* gA;   // eU + (row0 + rowl)*1024 + seg*16   (per-lane)
  const char* gB;   // cU + (col0 + rowl)*1024 + seg*16   (per-lane)
  char* lA;         // ldsA + wv*1024                      (wave-uniform)
  char* lB;         // ldsB + wv*1024
};

__device__ __forceinline__ void stage_A(const Pipe& p, int tt, int hi) {
  char* d = p.lA + ((tt & 1) << 15) + hi * 16384;
  const char* g = p.gA + tt * 128 + hi * 131072;
  gload_lds16(g, d);
  gload_lds16(g + 65536, d + 8192);
}
__device__ __forceinline__ void stage_B(const Pipe& p, int tt, int hi) {
  char* d = p.lB + ((tt & 1) << 15) + hi * 16384;
  const char* g = p.gB + tt * 128 + hi * 131072;
  gload_lds16(g, d);
  gload_lds16(g + 65536, d + 8192);
}

template <int MI0, int NJ0>
__device__ __forceinline__ void mfma_quad(f32x4 acc[8][4], const bf16x8 af[4][2],
                                          const bf16x8 bf[4][2]) {
  __builtin_amdgcn_s_setprio(1);
  #pragma unroll
  for (int kk = 0; kk < 2; ++kk)
    #pragma unroll
    for (int mi = 0; mi < 4; ++mi)
      #pragma unroll
      for (int nj = 0; nj < 2; ++nj)
        acc[MI0 + mi][NJ0 + nj] = __builtin_amdgcn_mfma_f32_16x16x32_bf16(
            af[mi][kk], bf[NJ0 + nj][kk], acc[MI0 + mi][NJ0 + nj], 0, 0, 0);
  __builtin_amdgcn_s_setprio(0);
}

__global__ __launch_bounds__(512, 2) void mfma_kernel(
    const char* __restrict__ eU, const char* __restrict__ cU,
    const float* __restrict__ pos, const float* __restrict__ wp,
    const float* __restrict__ bp, float* __restrict__ partial)
{
  __shared__ char ldsA[65536];
  __shared__ char ldsB[65536];
  __shared__ float pos_l[256];
  __shared__ float rowsum[4][256];

  const int t = threadIdx.x;
  const int lane = t & 63;
  const int wv = t >> 6;               // 0..7
  const int wm = wv >> 2, wn = wv & 3;

  // XCD swizzle (256 blocks, 8 XCDs)
  const int bid = blockIdx.x;
  const int sw = (bid & 7) * 32 + (bid >> 3);
  const int cb = sw & 3, rb = sw >> 2;
  const int row0 = rb * 256, col0 = cb * 256;

  const float w = *wp, b = *bp;        // uniform -> s_load (lgkm)
  const float bb = w * 1e-6f + b;

  if (t < 256) pos_l[t] = pos[row0 + t];

  // staging addresses: lane writes LDS slot tid*16 (HW: wave-base + lane*16);
  // source row = rowl = wv*8 + (lane>>3) (+64 per chunk), seg = (l&7)^(l>>3)
  Pipe p;
  {
    const int rowl = wv * 8 + (lane >> 3);
    const int seg = (lane & 7) ^ (lane >> 3);
    p.gA = eU + (size_t)(row0 + rowl) * 1024 + seg * 16;
    p.gB = cU + (size_t)(col0 + rowl) * 1024 + seg * 16;
    p.lA = ldsA + wv * 1024;
    p.lB = ldsB + wv * 1024;
  }

  // fragment read offsets: row j16 = lane&15, k-octet g = lane>>4
  const int j16 = lane & 15, g = lane >> 4;
  const int afb0 = (wm * 128 + j16) * 128 + (((0 * 4 + g) ^ (lane & 7)) * 16);
  const int afb1 = (wm * 128 + j16) * 128 + (((1 * 4 + g) ^ (lane & 7)) * 16);
  const int bfb0 = (wn * 64 + j16) * 128 + (((0 * 4 + g) ^ (lane & 7)) * 16);
  const int bfb1 = (wn * 64 + j16) * 128 + (((1 * 4 + g) ^ (lane & 7)) * 16);

  f32x4 acc[8][4] = {};
  bf16x8 af[4][2], bf[4][2];

  __syncthreads();   // pos_l visible + all prior vmem drained (exact counting)

  // prologue: idx 0..5 = B0lo,B0hi,A0lo,A0hi,B1lo,B1hi (12 loads)
  stage_B(p, 0, 0); stage_B(p, 0, 1);
  stage_A(p, 0, 0); stage_A(p, 0, 1);
  stage_B(p, 1, 0); stage_B(p, 1, 1);
  asm volatile("s_waitcnt vmcnt(4)" ::: "memory");   // B0+A0 landed; B1 flies
  __builtin_amdgcn_sched_barrier(0);
  barrier_pin();

  for (int j = 0; j < NKT; ++j) {
    const int bo = (j & 1) << 15;
    // ---- P0: af[mi 0-3], bf[nj 0-1]; stage A(j+1)-lo
    #pragma unroll
    for (int a = 0; a < 4; ++a) {
      af[a][0] = *reinterpret_cast<const bf16x8*>(ldsA + bo + afb0 + a * 2048);
      af[a][1] = *reinterpret_cast<const bf16x8*>(ldsA + bo + afb1 + a * 2048);
    }
    #pragma unroll
    for (int nq = 0; nq < 2; ++nq) {
      bf[nq][0] = *reinterpret_cast<const bf16x8*>(ldsB + bo + bfb0 + nq * 2048);
      bf[nq][1] = *reinterpret_cast<const bf16x8*>(ldsB + bo + bfb1 + nq * 2048);
    }
    if (j <= 6) stage_A(p, j + 1, 0);
    barrier_pin();
    lgkm0();
    mfma_quad<0, 0>(acc, af, bf);
    barrier_pin();
    // ---- P1: bf[nj 2-3]; stage A(j+1)-hi
    #pragma unroll
    for (int nq = 2; nq < 4; ++nq) {
      bf[nq][0] = *reinterpret_cast<const bf16x8*>(ldsB + bo + bfb0 + nq * 2048);
      bf[nq][1] = *reinterpret_cast<const bf16x8*>(ldsB + bo + bfb1 + nq * 2048);
    }
    if (j <= 6) stage_A(p, j + 1, 1);
    barrier_pin();
    lgkm0();
    mfma_quad<0, 2>(acc, af, bf);
    barrier_pin();
    // ---- P2: af[mi 4-7] (reuse regs); stage B(j+2)-lo (B(j) reads done @P1)
    #pragma unroll
    for (int a = 0; a < 4; ++a) {
      af[a][0] = *reinterpret_cast<const bf16x8*>(ldsA + bo + afb0 + (a + 4) * 2048);
      af[a][1] = *reinterpret_cast<const bf16x8*>(ldsA + bo + afb1 + (a + 4) * 2048);
    }
    if (j <= 5) stage_B(p, j + 2, 0);
    barrier_pin();
    lgkm0();
    mfma_quad<4, 0>(acc, af, bf);
    barrier_pin();
    // ---- P3: stage B(j+2)-hi; tile-boundary counted vmcnt for tile j+1
    if (j <= 5) stage_B(p, j + 2, 1);
    if (j < 7) {
      if (j == 6) { asm volatile("s_waitcnt vmcnt(0)" ::: "memory"); }
      else        { asm volatile("s_waitcnt vmcnt(4)" ::: "memory"); }
      __builtin_amdgcn_sched_barrier(0);
    }
    barrier_pin();
    mfma_quad<4, 2>(acc, af, bf);
    barrier_pin();
  }

  // fused epilogue: arg = w*acc + bb (diag -> pos), exp, per-row sums
  float esum[8][4];
  #pragma unroll
  for (int mi = 0; mi < 8; ++mi)
    #pragma unroll
    for (int rg = 0; rg < 4; ++rg) esum[mi][rg] = 0.f;

  #pragma unroll
  for (int nj = 0; nj < 4; ++nj) {
    const int kg = col0 + wn * 64 + nj * 16 + (lane & 15);
    #pragma unroll
    for (int mi = 0; mi < 8; ++mi) {
      #pragma unroll
      for (int rg = 0; rg < 4; ++rg) {
        const int r_loc = wm * 128 + mi * 16 + (lane >> 4) * 4 + rg;
        float arg = w * acc[mi][nj][rg] + bb;
        if (kg == ((row0 + r_loc) >> 4)) arg = pos_l[r_loc];
        esum[mi][rg] += __expf(arg);
      }
    }
  }
  #pragma unroll
  for (int mi = 0; mi < 8; ++mi)
    #pragma unroll
    for (int rg = 0; rg < 4; ++rg) {
      float v = esum[mi][rg];
      v += __shfl_xor(v, 1, 64);
      v += __shfl_xor(v, 2, 64);
      v += __shfl_xor(v, 4, 64);
      v += __shfl_xor(v, 8, 64);
      esum[mi][rg] = v;
    }
  if ((lane & 15) == 0) {
    #pragma unroll
    for (int mi = 0; mi < 8; ++mi)
      #pragma unroll
      for (int rg = 0; rg < 4; ++rg)
        rowsum[wn][wm * 128 + mi * 16 + (lane >> 4) * 4 + rg] = esum[mi][rg];
  }
  __syncthreads();
  if (t < 256)
    partial[(size_t)cb * (N_SPK * M_UTT) + row0 + t] =
        rowsum[0][t] + rowsum[1][t] + rowsum[2][t] + rowsum[3][t];
}

// Kernel 3: fused log-sum + global reduce, single block (deterministic).
__global__ __launch_bounds__(1024) void finalize_kernel(
    const float* __restrict__ partial, const float* __restrict__ pos,
    float* __restrict__ out)
{
  const int t = threadIdx.x;
  float v = 0.f;
  #pragma unroll
  for (int i = 0; i < 16; ++i) {
    const int r = t + i * 1024;
    float s = partial[r] + partial[16384 + r] + partial[32768 + r] +
              partial[49152 + r];
    v += logf(s + 1e-6f) - pos[r];
  }
  v = wave_sum64(v);
  __shared__ float red[16];
  if ((t & 63) == 0) red[t >> 6] = v;
  __syncthreads();
  if (t == 0) {
    float s = 0.f;
    #pragma unroll
    for (int i = 0; i < 16; ++i) s += red[i];
    out[0] = s;
  }
}

extern "C" void kernel_launch(void* const* d_in, const int* in_sizes, int n_in,
                              void* d_out, int out_size, void* d_ws, size_t ws_size,
                              hipStream_t stream) {
  const float* emb = (const float*)d_in[0];
  const float* wp  = (const float*)d_in[1];
  const float* bp  = (const float*)d_in[2];
  float* out = (float*)d_out;

  char* wsb = (char*)d_ws;
  unsigned int* eU  = (unsigned int*)wsb;                       // 16,777,216 B
  unsigned int* cU  = (unsigned int*)(wsb + 16777216);          //  1,048,576 B
  float* pos        = (float*)(wsb + 16777216 + 1048576);       //     65,536 B
  float* partial    = (float*)(wsb + 16777216 + 1048576 + 65536);   // 262,144 B

  prep_kernel<<<N_SPK, 256, 0, stream>>>(emb, wp, bp, eU, cU, pos);
  mfma_kernel<<<256, 512, 0, stream>>>(
      (const char*)eU, (const char*)cU, pos, wp, bp, partial);
  finalize_kernel<<<1, 1024, 0, stream>>>(partial, pos, out);
}